// Round 8
// baseline (819.478 us; speedup 1.0000x reference)
//
#include <hip/hip_runtime.h>
#include <hip/hip_bf16.h>
#include <math.h>

// B=4, N=512, H=128. out (4,512,512,128) fp32 = 537 MB.
//
// Layer-1 (18->128 + GELU) on VALU, wave-uniform W1 slices (s_loads);
// layer-2 (128x128) on MFMA via split-bf16 (hi/lo, 3-term).
// Block = 512 thr = 8 waves = one (b,m) row; 8 chunks of 64 pairs.
//
// R6 fixes vs R2-measured (446us, VGPR=60arch+~64acc, ~3.3k VALU/iter =
// AGPR<->VGPR shuffle bloat; FETCH_SIZE=2.5GB = write-allocate RMW):
//   1) no f[18] array: feature computed -> immediately FMA'd into x[16],
//      i-box uniforms forced to SGPR via readfirstlane. Peak arch-live ~50.
//   2) nontemporal output stores -> no L2 read-for-ownership.

#define BB 4
#define NN 512
#define HH 128

typedef __attribute__((ext_vector_type(8))) short bf16x8;
typedef __attribute__((ext_vector_type(4))) float f32x4;

__device__ __forceinline__ unsigned short bf16_rne(float x) {
    unsigned int u = __float_as_uint(x);
    unsigned int r = u + 0x7FFFu + ((u >> 16) & 1u);
    return (unsigned short)(r >> 16);
}

__device__ __forceinline__ float sgpr_f(float x) {
    return __uint_as_float(__builtin_amdgcn_readfirstlane(__float_as_uint(x)));
}

// Abramowitz-Stegun 7.1.26: abs err <= 1.5e-7, branch-free.
__device__ __forceinline__ float erf_fast(float x) {
    const float ax = fabsf(x);
    const float t  = __builtin_amdgcn_rcpf(fmaf(0.3275911f, ax, 1.0f));
    float p = fmaf(1.061405429f, t, -1.453152027f);
    p = fmaf(p, t, 1.421413741f);
    p = fmaf(p, t, -0.284496736f);
    p = fmaf(p, t, 0.254829592f);
    p = p * t;
    const float e = __builtin_amdgcn_exp2f((ax * -1.44269504088896f) * ax);
    const float r = fmaf(-p, e, 1.0f);
    return copysignf(r, x);
}

__device__ __forceinline__ float gelu_exact(float x) {
    return 0.5f * x * (1.0f + erf_fast(x * 0.70710678118654752f));
}

__global__ __launch_bounds__(512, 2) void spatial_mlp_mfma(
    const float* __restrict__ bbox_i,  // (B,N,4)
    const float* __restrict__ bbox_j,  // (B,N,4)
    const float* __restrict__ W1,      // (18,H)
    const float* __restrict__ b1,      // (H)
    const float* __restrict__ W2,      // (H,H)
    const float* __restrict__ b2,      // (H)
    float* __restrict__ out)           // (B,N,N,H)
{
    __shared__ unsigned short Ah[2][64][HH];
    __shared__ unsigned short Al[2][64][HH];

    const int tid  = threadIdx.x;
    const int lane = tid & 63;
    const int w    = tid >> 6;        // wave 0..7 (owns out-cols 16w..16w+16)
    const int g    = lane >> 4;       // k-group 0..3
    const int l15  = lane & 15;

    const int bid   = blockIdx.x;         // b*512 + m
    const int jbase = (bid >> 9) << 9;    // b*512

    // ---- one-time: W2 fragments for this wave's 16 columns, bf16 hi/lo ----
    const int col = (w << 4) + l15;
    bf16x8 bh[4], bl[4];
#pragma unroll
    for (int kb = 0; kb < 4; ++kb) {
#pragma unroll
        for (int e = 0; e < 8; ++e) {
            const float v = W2[(kb * 32 + g * 8 + e) * HH + col];
            const unsigned short hi = bf16_rne(v);
            const float lo = v - __uint_as_float((unsigned int)hi << 16);
            bh[kb][e] = (short)hi;
            bl[kb][e] = (short)bf16_rne(lo);
        }
    }
    const float b2c = b2[col];

    // box i: block-uniform -> force into SGPRs (no arch-VGPR cost)
    const float4 bi = *reinterpret_cast<const float4*>(bbox_i + (size_t)bid * 4);
    const float x1i = sgpr_f(bi.x), y1i = sgpr_f(bi.y);
    const float x2i = sgpr_f(bi.z), y2i = sgpr_f(bi.w);
    const float wi  = sgpr_f(x2i - x1i), hi_ = sgpr_f(y2i - y1i);
    const float cxi = sgpr_f((x1i + x2i) * 0.5f), cyi = sgpr_f((y1i + y2i) * 0.5f);
    const float lwi  = sgpr_f(__logf(wi + 1.0f));
    const float lhi  = sgpr_f(__logf(hi_ + 1.0f));
    const float lahi = sgpr_f(__logf(wi * hi_ + 1.0f));

    // wave-uniform hidden slice base -> scalar W1/b1 loads
    const int hh0 = __builtin_amdgcn_readfirstlane(w << 4);

    for (int it = 0; it < 8; ++it) {
        const int buf = it & 1;
        const int n0  = it << 6;

        // ---- per-pair box j ----
        const float4 bj = *reinterpret_cast<const float4*>(
            bbox_j + (size_t)(jbase + n0 + lane) * 4);
        const float x1j = bj.x, y1j = bj.y, x2j = bj.z, y2j = bj.w;
        const float wj = x2j - x1j, hj = y2j - y1j;
        const float cxj = (x1j + x2j) * 0.5f, cyj = (y1j + y2j) * 0.5f;
        const float dcx = cxj - cxi, dcy = cyj - cyi;

        // ---- layer 1 accumulators; features folded in one at a time ----
        float x[16];
#pragma unroll
        for (int e = 0; e < 16; ++e) x[e] = b1[hh0 + e];

#define FPUT(FF, FV)                                                     \
        {                                                                \
            const float fv_ = (FV);                                      \
            _Pragma("unroll")                                            \
            for (int e = 0; e < 16; ++e)                                 \
                x[e] = fmaf(fv_, W1[(FF) * HH + hh0 + e], x[e]);         \
        }

        FPUT(0,  dcx)
        FPUT(1,  dcy)
        FPUT(2,  x1j - x1i)
        FPUT(3,  y1j - y1i)
        FPUT(4,  x2j - x2i)
        FPUT(5,  y2j - y2i)
        FPUT(6,  __logf(wj + 1.0f) - lwi)
        FPUT(7,  __logf(hj + 1.0f) - lhi)
        FPUT(8,  fmaxf(fminf(x2i, x2j) - fmaxf(x1i, x1j), 0.0f))
        FPUT(9,  fmaxf(fminf(y2i, y2j) - fmaxf(y1i, y1j), 0.0f))
        FPUT(10, __builtin_amdgcn_sqrtf(fmaf(dcx, dcx, fmaf(dcy, dcy, 1e-6f))))
        FPUT(11, fabsf(dcx))
        FPUT(12, fabsf(dcy))
        FPUT(13, (cxj > cxi) ? 1.0f : 0.0f)
        FPUT(14, (cyj > cyi) ? 1.0f : 0.0f)
        FPUT(15, (x1j > x2i) ? 1.0f : 0.0f)
        FPUT(16, (y1j > y2i) ? 1.0f : 0.0f)
        FPUT(17, __logf(wj * hj + 1.0f) - lahi)
#undef FPUT

        // ---- GELU + bf16 hi/lo split, packed two-per-dword ----
        unsigned int hiw[8], low[8];
#pragma unroll
        for (int e2 = 0; e2 < 8; ++e2) {
            const float g0 = gelu_exact(x[2 * e2]);
            const float g1 = gelu_exact(x[2 * e2 + 1]);
            const unsigned int h0 = bf16_rne(g0);
            const unsigned int h1 = bf16_rne(g1);
            const float r0 = g0 - __uint_as_float(h0 << 16);
            const float r1 = g1 - __uint_as_float(h1 << 16);
            hiw[e2] = h0 | ((unsigned int)h1 << 16);
            low[e2] = (unsigned int)bf16_rne(r0) |
                      ((unsigned int)bf16_rne(r1) << 16);
        }

        // ---- LDS write, row = pair = lane, XOR slot swizzle ----
        {
            char* ahp = (char*)Ah + buf * 16384 + lane * 256;
            char* alp = (char*)Al + buf * 16384 + lane * 256;
            const int s0 = ((2 * w + 0) ^ l15) << 4;
            const int s1 = ((2 * w + 1) ^ l15) << 4;
            *reinterpret_cast<uint4*>(ahp + s0) = make_uint4(hiw[0], hiw[1], hiw[2], hiw[3]);
            *reinterpret_cast<uint4*>(ahp + s1) = make_uint4(hiw[4], hiw[5], hiw[6], hiw[7]);
            *reinterpret_cast<uint4*>(alp + s0) = make_uint4(low[0], low[1], low[2], low[3]);
            *reinterpret_cast<uint4*>(alp + s1) = make_uint4(low[4], low[5], low[6], low[7]);
        }

        __syncthreads();

        // ---- layer 2: 4 pair-tiles x 4 k-blocks x 3 split MFMAs ----
        const char* ah_base = (const char*)Ah + buf * 16384;
        const char* al_base = (const char*)Al + buf * 16384;
#pragma unroll
        for (int pt = 0; pt < 4; ++pt) {
            f32x4 acc = {b2c, b2c, b2c, b2c};
            const int row = pt * 16 + l15;
#pragma unroll
            for (int kb = 0; kb < 4; ++kb) {
                const int off = row * 256 + (((kb * 4 + g) ^ l15) << 4);
                const bf16x8 ah = *reinterpret_cast<const bf16x8*>(ah_base + off);
                const bf16x8 al = *reinterpret_cast<const bf16x8*>(al_base + off);
                acc = __builtin_amdgcn_mfma_f32_16x16x32_bf16(ah, bh[kb], acc, 0, 0, 0);
                acc = __builtin_amdgcn_mfma_f32_16x16x32_bf16(ah, bl[kb], acc, 0, 0, 0);
                acc = __builtin_amdgcn_mfma_f32_16x16x32_bf16(al, bh[kb], acc, 0, 0, 0);
            }
            // store: row-in-chunk = 16pt + 4g + r, col = 16w + l15 (m89 C/D map)
            // nontemporal: no L2 write-allocate RMW fetch.
            float* o = out + (size_t)(bid * 512 + n0 + pt * 16 + g * 4) * HH + col;
#pragma unroll
            for (int r = 0; r < 4; ++r)
                __builtin_nontemporal_store(acc[r], o + (size_t)r * HH);
        }
    }
}

extern "C" void kernel_launch(void* const* d_in, const int* in_sizes, int n_in,
                              void* d_out, int out_size, void* d_ws, size_t ws_size,
                              hipStream_t stream) {
    const float* bbox_i = (const float*)d_in[0];
    const float* bbox_j = (const float*)d_in[1];
    const float* W1     = (const float*)d_in[2];
    const float* b1     = (const float*)d_in[3];
    const float* W2     = (const float*)d_in[4];
    const float* b2     = (const float*)d_in[5];
    float* out = (float*)d_out;

    spatial_mlp_mfma<<<BB * NN, 512, 0, stream>>>(bbox_i, bbox_j, W1, b1, W2, b2, out);
}

// Round 9
// 747.926 us; speedup vs baseline: 1.0957x; 1.0957x over previous
//
#include <hip/hip_runtime.h>
#include <hip/hip_bf16.h>
#include <math.h>

// B=4, N=512, H=128. out (4,512,512,128) fp32 = 537 MB.
//
// Layer-1 (18->128 + GELU) on VALU; layer-2 (128x128) on MFMA via
// split-bf16 (hi/lo, 3-term). Block = 512 thr = 8 waves = one (b,m) row;
// 8 chunks of 64 pairs.
//
// R8 history: nontemporal stores killed the 2.5GB RMW fetch (R6 fix 2, WIN);
// f[18] elimination was NULL -> VALU cost is NOT reg shuffles.
// R8 theory: the ~4x VALU/latency bloat is the 288 per-iter W1/b1 global
// loads (unhoistable, re-issued every chunk). Fix: stage W1+b1 into LDS
// once per block; inner loop reads them via uniform-address ds_read_b128
// (broadcast, no VMEM, no address VALU).

#define BB 4
#define NN 512
#define HH 128
#define W1_ELEMS (18 * HH)          // 2304
#define W1S_TOTAL (W1_ELEMS + HH)   // + b1 -> 2432 floats = 9728 B

typedef __attribute__((ext_vector_type(8))) short bf16x8;
typedef __attribute__((ext_vector_type(4))) float f32x4;

__device__ __forceinline__ unsigned short bf16_rne(float x) {
    unsigned int u = __float_as_uint(x);
    unsigned int r = u + 0x7FFFu + ((u >> 16) & 1u);
    return (unsigned short)(r >> 16);
}

__device__ __forceinline__ float sgpr_f(float x) {
    return __uint_as_float(__builtin_amdgcn_readfirstlane(__float_as_uint(x)));
}

// Abramowitz-Stegun 7.1.26: abs err <= 1.5e-7, branch-free.
__device__ __forceinline__ float erf_fast(float x) {
    const float ax = fabsf(x);
    const float t  = __builtin_amdgcn_rcpf(fmaf(0.3275911f, ax, 1.0f));
    float p = fmaf(1.061405429f, t, -1.453152027f);
    p = fmaf(p, t, 1.421413741f);
    p = fmaf(p, t, -0.284496736f);
    p = fmaf(p, t, 0.254829592f);
    p = p * t;
    const float e = __builtin_amdgcn_exp2f((ax * -1.44269504088896f) * ax);
    const float r = fmaf(-p, e, 1.0f);
    return copysignf(r, x);
}

__device__ __forceinline__ float gelu_exact(float x) {
    return 0.5f * x * (1.0f + erf_fast(x * 0.70710678118654752f));
}

// 16 FMAs with 16 consecutive LDS-resident weights (4x ds_read_b128).
__device__ __forceinline__ void fma16(float* __restrict__ x, float fv,
                                      const float* __restrict__ w) {
    const float4 wa = *reinterpret_cast<const float4*>(w + 0);
    const float4 wb = *reinterpret_cast<const float4*>(w + 4);
    const float4 wc = *reinterpret_cast<const float4*>(w + 8);
    const float4 wd = *reinterpret_cast<const float4*>(w + 12);
    x[0]  = fmaf(fv, wa.x, x[0]);  x[1]  = fmaf(fv, wa.y, x[1]);
    x[2]  = fmaf(fv, wa.z, x[2]);  x[3]  = fmaf(fv, wa.w, x[3]);
    x[4]  = fmaf(fv, wb.x, x[4]);  x[5]  = fmaf(fv, wb.y, x[5]);
    x[6]  = fmaf(fv, wb.z, x[6]);  x[7]  = fmaf(fv, wb.w, x[7]);
    x[8]  = fmaf(fv, wc.x, x[8]);  x[9]  = fmaf(fv, wc.y, x[9]);
    x[10] = fmaf(fv, wc.z, x[10]); x[11] = fmaf(fv, wc.w, x[11]);
    x[12] = fmaf(fv, wd.x, x[12]); x[13] = fmaf(fv, wd.y, x[13]);
    x[14] = fmaf(fv, wd.z, x[14]); x[15] = fmaf(fv, wd.w, x[15]);
}

__global__ __launch_bounds__(512, 2) void spatial_mlp_mfma(
    const float* __restrict__ bbox_i,  // (B,N,4)
    const float* __restrict__ bbox_j,  // (B,N,4)
    const float* __restrict__ W1,      // (18,H)
    const float* __restrict__ b1,      // (H)
    const float* __restrict__ W2,      // (H,H)
    const float* __restrict__ b2,      // (H)
    float* __restrict__ out)           // (B,N,N,H)
{
    __shared__ unsigned short Ah[2][64][HH];
    __shared__ unsigned short Al[2][64][HH];
    __shared__ float W1s[W1S_TOTAL];   // W1 row-major, then b1

    const int tid  = threadIdx.x;
    const int lane = tid & 63;
    const int w    = tid >> 6;        // wave 0..7 (owns out-cols 16w..16w+16)
    const int g    = lane >> 4;       // k-group 0..3
    const int l15  = lane & 15;

    const int bid   = blockIdx.x;         // b*512 + m
    const int jbase = (bid >> 9) << 9;    // b*512

    // ---- one-time: stage W1 + b1 into LDS ----
    for (int i = tid; i < W1S_TOTAL; i += 512)
        W1s[i] = (i < W1_ELEMS) ? W1[i] : b1[i - W1_ELEMS];

    // ---- one-time: W2 fragments for this wave's 16 columns, bf16 hi/lo ----
    const int col = (w << 4) + l15;
    bf16x8 bh[4], bl[4];
#pragma unroll
    for (int kb = 0; kb < 4; ++kb) {
#pragma unroll
        for (int e = 0; e < 8; ++e) {
            const float v = W2[(kb * 32 + g * 8 + e) * HH + col];
            const unsigned short hi = bf16_rne(v);
            const float lo = v - __uint_as_float((unsigned int)hi << 16);
            bh[kb][e] = (short)hi;
            bl[kb][e] = (short)bf16_rne(lo);
        }
    }
    const float b2c = b2[col];

    // box i: block-uniform -> force into SGPRs
    const float4 bi = *reinterpret_cast<const float4*>(bbox_i + (size_t)bid * 4);
    const float x1i = sgpr_f(bi.x), y1i = sgpr_f(bi.y);
    const float x2i = sgpr_f(bi.z), y2i = sgpr_f(bi.w);
    const float wi  = sgpr_f(x2i - x1i), hi_ = sgpr_f(y2i - y1i);
    const float cxi = sgpr_f((x1i + x2i) * 0.5f), cyi = sgpr_f((y1i + y2i) * 0.5f);
    const float lwi  = sgpr_f(__logf(wi + 1.0f));
    const float lhi  = sgpr_f(__logf(hi_ + 1.0f));
    const float lahi = sgpr_f(__logf(wi * hi_ + 1.0f));

    // wave-uniform hidden slice base
    const int hh0 = __builtin_amdgcn_readfirstlane(w << 4);
    const float* __restrict__ w1sl = W1s + hh0;           // W1 slice base
    const float* __restrict__ b1sl = W1s + W1_ELEMS + hh0; // b1 slice base

    __syncthreads();   // W1s ready

    for (int it = 0; it < 8; ++it) {
        const int buf = it & 1;
        const int n0  = it << 6;

        // ---- per-pair box j ----
        const float4 bj = *reinterpret_cast<const float4*>(
            bbox_j + (size_t)(jbase + n0 + lane) * 4);
        const float x1j = bj.x, y1j = bj.y, x2j = bj.z, y2j = bj.w;
        const float wj = x2j - x1j, hj = y2j - y1j;
        const float cxj = (x1j + x2j) * 0.5f, cyj = (y1j + y2j) * 0.5f;
        const float dcx = cxj - cxi, dcy = cyj - cyi;

        // ---- layer 1 accumulators seeded with b1 (LDS broadcast) ----
        float x[16];
        {
            const float4 ba = *reinterpret_cast<const float4*>(b1sl + 0);
            const float4 bb = *reinterpret_cast<const float4*>(b1sl + 4);
            const float4 bc = *reinterpret_cast<const float4*>(b1sl + 8);
            const float4 bd = *reinterpret_cast<const float4*>(b1sl + 12);
            x[0]=ba.x; x[1]=ba.y; x[2]=ba.z; x[3]=ba.w;
            x[4]=bb.x; x[5]=bb.y; x[6]=bb.z; x[7]=bb.w;
            x[8]=bc.x; x[9]=bc.y; x[10]=bc.z; x[11]=bc.w;
            x[12]=bd.x; x[13]=bd.y; x[14]=bd.z; x[15]=bd.w;
        }

#define FPUT(FF, FV) fma16(x, (FV), w1sl + (FF) * HH);
        FPUT(0,  dcx)
        FPUT(1,  dcy)
        FPUT(2,  x1j - x1i)
        FPUT(3,  y1j - y1i)
        FPUT(4,  x2j - x2i)
        FPUT(5,  y2j - y2i)
        FPUT(6,  __logf(wj + 1.0f) - lwi)
        FPUT(7,  __logf(hj + 1.0f) - lhi)
        FPUT(8,  fmaxf(fminf(x2i, x2j) - fmaxf(x1i, x1j), 0.0f))
        FPUT(9,  fmaxf(fminf(y2i, y2j) - fmaxf(y1i, y1j), 0.0f))
        FPUT(10, __builtin_amdgcn_sqrtf(fmaf(dcx, dcx, fmaf(dcy, dcy, 1e-6f))))
        FPUT(11, fabsf(dcx))
        FPUT(12, fabsf(dcy))
        FPUT(13, (cxj > cxi) ? 1.0f : 0.0f)
        FPUT(14, (cyj > cyi) ? 1.0f : 0.0f)
        FPUT(15, (x1j > x2i) ? 1.0f : 0.0f)
        FPUT(16, (y1j > y2i) ? 1.0f : 0.0f)
        FPUT(17, __logf(wj * hj + 1.0f) - lahi)
#undef FPUT

        // ---- GELU + bf16 hi/lo split, packed two-per-dword ----
        unsigned int hiw[8], low[8];
#pragma unroll
        for (int e2 = 0; e2 < 8; ++e2) {
            const float g0 = gelu_exact(x[2 * e2]);
            const float g1 = gelu_exact(x[2 * e2 + 1]);
            const unsigned int h0 = bf16_rne(g0);
            const unsigned int h1 = bf16_rne(g1);
            const float r0 = g0 - __uint_as_float(h0 << 16);
            const float r1 = g1 - __uint_as_float(h1 << 16);
            hiw[e2] = h0 | ((unsigned int)h1 << 16);
            low[e2] = (unsigned int)bf16_rne(r0) |
                      ((unsigned int)bf16_rne(r1) << 16);
        }

        // ---- LDS write, row = pair = lane, XOR slot swizzle ----
        {
            char* ahp = (char*)Ah + buf * 16384 + lane * 256;
            char* alp = (char*)Al + buf * 16384 + lane * 256;
            const int s0 = ((2 * w + 0) ^ l15) << 4;
            const int s1 = ((2 * w + 1) ^ l15) << 4;
            *reinterpret_cast<uint4*>(ahp + s0) = make_uint4(hiw[0], hiw[1], hiw[2], hiw[3]);
            *reinterpret_cast<uint4*>(ahp + s1) = make_uint4(hiw[4], hiw[5], hiw[6], hiw[7]);
            *reinterpret_cast<uint4*>(alp + s0) = make_uint4(low[0], low[1], low[2], low[3]);
            *reinterpret_cast<uint4*>(alp + s1) = make_uint4(low[4], low[5], low[6], low[7]);
        }

        __syncthreads();

        // ---- layer 2: 4 pair-tiles x 4 k-blocks x 3 split MFMAs ----
        const char* ah_base = (const char*)Ah + buf * 16384;
        const char* al_base = (const char*)Al + buf * 16384;
#pragma unroll
        for (int pt = 0; pt < 4; ++pt) {
            f32x4 acc = {b2c, b2c, b2c, b2c};
            const int row = pt * 16 + l15;
#pragma unroll
            for (int kb = 0; kb < 4; ++kb) {
                const int off = row * 256 + (((kb * 4 + g) ^ l15) << 4);
                const bf16x8 ah = *reinterpret_cast<const bf16x8*>(ah_base + off);
                const bf16x8 al = *reinterpret_cast<const bf16x8*>(al_base + off);
                acc = __builtin_amdgcn_mfma_f32_16x16x32_bf16(ah, bh[kb], acc, 0, 0, 0);
                acc = __builtin_amdgcn_mfma_f32_16x16x32_bf16(ah, bl[kb], acc, 0, 0, 0);
                acc = __builtin_amdgcn_mfma_f32_16x16x32_bf16(al, bh[kb], acc, 0, 0, 0);
            }
            // store: row-in-chunk = 16pt + 4g + r, col = 16w + l15 (m89 C/D map)
            float* o = out + (size_t)(bid * 512 + n0 + pt * 16 + g * 4) * HH + col;
#pragma unroll
            for (int r = 0; r < 4; ++r)
                __builtin_nontemporal_store(acc[r], o + (size_t)r * HH);
        }
    }
}

extern "C" void kernel_launch(void* const* d_in, const int* in_sizes, int n_in,
                              void* d_out, int out_size, void* d_ws, size_t ws_size,
                              hipStream_t stream) {
    const float* bbox_i = (const float*)d_in[0];
    const float* bbox_j = (const float*)d_in[1];
    const float* W1     = (const float*)d_in[2];
    const float* b1     = (const float*)d_in[3];
    const float* W2     = (const float*)d_in[4];
    const float* b2     = (const float*)d_in[5];
    float* out = (float*)d_out;

    spatial_mlp_mfma<<<BB * NN, 512, 0, stream>>>(bbox_i, bbox_j, W1, b1, W2, b2, out);
}